// Round 7
// baseline (323.147 us; speedup 1.0000x reference)
//
#include <hip/hip_runtime.h>

static __device__ inline float b2f(unsigned short u){
  union { unsigned int i; float f; } v; v.i = ((unsigned int)u) << 16; return v.f;
}
static __device__ inline unsigned short f2b(float f){
  union { float ff; unsigned int u; } v; v.ff = f;
  unsigned int xx = v.u;
  return (unsigned short)((xx + 0x7fffu + ((xx >> 16) & 1u)) >> 16);
}

typedef __attribute__((ext_vector_type(8))) short short8x;   // 8 bf16 (4 VGPRs)
typedef __attribute__((ext_vector_type(4))) float f32x4;
typedef __attribute__((ext_vector_type(2))) float float2v;   // -> v_pk_*_f32

// unpack one dword holding 2 bf16 -> float2 {lo, hi}
static __device__ inline float2v up2(unsigned int u){
  union { unsigned int i; float f; } a, b;
  a.i = u << 16; b.i = u & 0xffff0000u;
  float2v r; r.x = a.f; r.y = b.f; return r;
}

// 8-lane sum via DPP (VALU-only). Requires whole wave active (wave-uniform guards).
#define DPPADD(x, ctrl) \
  ((x) + __int_as_float(__builtin_amdgcn_update_dpp(0, __float_as_int(x), (ctrl), 0xf, 0xf, true)))
static __device__ inline float red8(float x){
  x = DPPADD(x, 0xb1);    // quad_perm [1,0,3,2]
  x = DPPADD(x, 0x4e);    // quad_perm [2,3,0,1]
  x = DPPADD(x, 0x141);   // row_half_mirror
  return x;
}

// ---------------- shared phase bodies ----------------

// Wg^T pack item (idx in [0,16384))
static __device__ inline void dev_wpack1_item(int idx, const float* __restrict__ Wg,
                                              unsigned short* __restrict__ wp1){
  int i    = idx & 7;
  int lane = (idx >> 3) & 63;
  int p    = (idx >> 9) & 1;
  int kt   = (idx >> 10) & 3;
  int ct   = idx >> 12;                            // 0..3
  int c = ct * 16 + (lane & 15);
  int k = kt * 32 + (lane >> 4) * 8 + i;
  float w = Wg[k * 64 + c];
  unsigned short hi = f2b(w);
  unsigned short outv = p ? f2b(w - b2f(hi)) : hi;
  int fb = ct * 8 + kt * 2 + p;
  wp1[(size_t)fb * 512 + lane * 8 + i] = outv;
}

// [Wl|Wr]^T pack item (idx in [0,65536))
static __device__ inline void dev_wpack2_item(int idx, const float* __restrict__ Wl,
                                              const float* __restrict__ Wr,
                                              unsigned short* __restrict__ wp){
  int i    = idx & 7;
  int lane = (idx >> 3) & 63;
  int p    = (idx >> 9) & 1;
  int kt   = (idx >> 10) & 1;
  int ct   = idx >> 11;                            // 0..31
  int c = ct * 16 + (lane & 15);
  int k = kt * 32 + (lane >> 4) * 8 + i;
  float w = (c < 256) ? Wl[k * 256 + c] : Wr[k * 256 + (c - 256)];
  unsigned short hi = f2b(w);
  unsigned short outv = p ? f2b(w - b2f(hi)) : hi;
  int fb = ct * 4 + kt * 2 + p;
  wp[(size_t)fb * 512 + lane * 8 + i] = outv;
}

// gemm1: virtual block vb covers 64 rows. D' = Wg^T . x^T via 16x16x32 MFMA.
static __device__ inline void dev_gemm1(int vb, int t, const float* __restrict__ x,
                                        const unsigned short* __restrict__ wp1,
                                        unsigned short* __restrict__ xw, int N){
  int lane = t & 63;
  int l15 = lane & 15;
  int lg = lane >> 4;
  int row = vb * 64 + (t >> 6) * 16 + l15;
  int rc = row < N ? row : N - 1;
  const float* xp = x + (size_t)rc * 128 + lg * 8;

  short8x xh[4], xlo[4];
  #pragma unroll
  for (int kt = 0; kt < 4; kt++){
    float4 a = *(const float4*)(xp + kt * 32);
    float4 b = *(const float4*)(xp + kt * 32 + 4);
    unsigned int h0, h1, h2, h3;
    asm("v_cvt_pk_bf16_f32 %0, %1, %2" : "=v"(h0) : "v"(a.x), "v"(a.y));
    asm("v_cvt_pk_bf16_f32 %0, %1, %2" : "=v"(h1) : "v"(a.z), "v"(a.w));
    asm("v_cvt_pk_bf16_f32 %0, %1, %2" : "=v"(h2) : "v"(b.x), "v"(b.y));
    asm("v_cvt_pk_bf16_f32 %0, %1, %2" : "=v"(h3) : "v"(b.z), "v"(b.w));
    union { unsigned int u[4]; short8x v; } H;
    H.u[0] = h0; H.u[1] = h1; H.u[2] = h2; H.u[3] = h3;
    xh[kt] = H.v;
    union { unsigned int u; float ff; } q;
    float r0, r1, r2, r3, r4, r5, r6, r7;
    q.u = h0 << 16;          r0 = a.x - q.ff;
    q.u = h0 & 0xffff0000u;  r1 = a.y - q.ff;
    q.u = h1 << 16;          r2 = a.z - q.ff;
    q.u = h1 & 0xffff0000u;  r3 = a.w - q.ff;
    q.u = h2 << 16;          r4 = b.x - q.ff;
    q.u = h2 & 0xffff0000u;  r5 = b.y - q.ff;
    q.u = h3 << 16;          r6 = b.z - q.ff;
    q.u = h3 & 0xffff0000u;  r7 = b.w - q.ff;
    unsigned int l0, l1, l2, l3;
    asm("v_cvt_pk_bf16_f32 %0, %1, %2" : "=v"(l0) : "v"(r0), "v"(r1));
    asm("v_cvt_pk_bf16_f32 %0, %1, %2" : "=v"(l1) : "v"(r2), "v"(r3));
    asm("v_cvt_pk_bf16_f32 %0, %1, %2" : "=v"(l2) : "v"(r4), "v"(r5));
    asm("v_cvt_pk_bf16_f32 %0, %1, %2" : "=v"(l3) : "v"(r6), "v"(r7));
    union { unsigned int u[4]; short8x v; } L;
    L.u[0] = l0; L.u[1] = l1; L.u[2] = l2; L.u[3] = l3;
    xlo[kt] = L.v;
  }

  #pragma unroll
  for (int ct = 0; ct < 4; ct++){
    f32x4 acc = {0.f, 0.f, 0.f, 0.f};
    #pragma unroll
    for (int kt = 0; kt < 4; kt++){
      const unsigned short* ap = wp1 + (size_t)(ct * 8 + kt * 2) * 512 + (size_t)lane * 8;
      short8x wh = *(const short8x*)(ap);
      short8x wl = *(const short8x*)(ap + 512);
      acc = __builtin_amdgcn_mfma_f32_16x16x32_bf16(wh, xh[kt], acc, 0, 0, 0);
      acc = __builtin_amdgcn_mfma_f32_16x16x32_bf16(wl, xh[kt], acc, 0, 0, 0);
      acc = __builtin_amdgcn_mfma_f32_16x16x32_bf16(wh, xlo[kt], acc, 0, 0, 0);
    }
    unsigned int p01, p23;
    asm("v_cvt_pk_bf16_f32 %0, %1, %2" : "=v"(p01) : "v"(acc[0]), "v"(acc[1]));
    asm("v_cvt_pk_bf16_f32 %0, %1, %2" : "=v"(p23) : "v"(acc[2]), "v"(acc[3]));
    if (row < N){
      uint2 pv; pv.x = p01; pv.y = p23;
      *(uint2*)(xw + (size_t)row * 64 + ct * 16 + lg * 4) = pv;
    }
  }
}

// ---------------- kernels ----------------

// init (zero cnt/cursor) + weight packing, disjoint block ranges
__global__ __launch_bounds__(256) void CarbonGNN_36447092474498_initpack(
    int* __restrict__ cnt, int* __restrict__ cursor, int N, int nbN,
    const float* __restrict__ Wg, const float* __restrict__ Wl,
    const float* __restrict__ Wr,
    unsigned short* __restrict__ wp1, unsigned short* __restrict__ wp){
  int b = blockIdx.x;
  if (b < nbN){
    int i = b * 256 + threadIdx.x;
    if (i < N){ cnt[i] = 0; cursor[i] = 0; }
  } else if (b < nbN + 64){
    dev_wpack1_item((b - nbN) * 256 + threadIdx.x, Wg, wp1);
  } else {
    dev_wpack2_item((b - nbN - 64) * 256 + threadIdx.x, Wl, Wr, wp);
  }
}

// degree histogram + gemm1 (independent), disjoint block ranges
__global__ __launch_bounds__(256) void CarbonGNN_36447092474498_histgemm1(
    const int* __restrict__ dst, int E, int* __restrict__ cnt, int nbE,
    const float* __restrict__ x, const unsigned short* __restrict__ wp1,
    unsigned short* __restrict__ xw, int N){
  int b = blockIdx.x;
  if (b < nbE){
    int e = b * 256 + threadIdx.x;
    if (e < E) atomicAdd(&cnt[dst[e]], 1);
  } else {
    dev_gemm1(b - nbE, threadIdx.x, x, wp1, xw, N);
  }
}

__global__ __launch_bounds__(256) void CarbonGNN_36447092474498_scan1(
    const int* __restrict__ cnt, int n, int* __restrict__ excl, int* __restrict__ bsum){
  __shared__ int sm[256];
  int t = threadIdx.x;
  int i = blockIdx.x * 256 + t;
  int v = (i < n) ? cnt[i] : 0;
  sm[t] = v;
  __syncthreads();
  for (int ofs = 1; ofs < 256; ofs <<= 1){
    int y = (t >= ofs) ? sm[t - ofs] : 0;
    __syncthreads();
    sm[t] += y;
    __syncthreads();
  }
  if (i < n) excl[i] = sm[t] - v;
  if (t == 255) bsum[blockIdx.x] = sm[t];
}

__global__ __launch_bounds__(256) void CarbonGNN_36447092474498_scan3(
    const int* __restrict__ excl, const int* __restrict__ bsum, int nb,
    const int* __restrict__ cnt, int n, int E,
    int* __restrict__ off, float* __restrict__ dinv){
  __shared__ int sm[256];
  int t = threadIdx.x;
  int v = (t < nb) ? bsum[t] : 0;
  sm[t] = v;
  __syncthreads();
  for (int ofs = 1; ofs < 256; ofs <<= 1){
    int y = (t >= ofs) ? sm[t - ofs] : 0;
    __syncthreads();
    sm[t] += y;
    __syncthreads();
  }
  int bofs = (blockIdx.x == 0) ? 0 : sm[blockIdx.x - 1];
  int i = blockIdx.x * 256 + t;
  if (i < n){
    off[i] = excl[i] + bofs;
    int c = cnt[i];
    dinv[i] = (c >= 0 && c <= E) ? rsqrtf((float)(c + 1)) : 1.0f;
  }
  if (i == 0) off[n] = E;
}

__global__ __launch_bounds__(256) void CarbonGNN_36447092474498_fill(
    const int* __restrict__ src, const int* __restrict__ dst, int E,
    const int* __restrict__ off, int* __restrict__ cursor, int* __restrict__ csr){
  int e = blockIdx.x * 256 + threadIdx.x;
  if (e < E){
    int d = dst[e];
    int p = atomicAdd(&cursor[d], 1);
    csr[off[d] + p] = src[e];
  }
}

// Fused GCN + gemm2: one 512-thread block covers 128 nodes.
// Phase A: 8 waves x 16 nodes each — eighth-wave GCN gather into LDS
//   hsm[128][72] bf16 (stride 72: rows 16B-aligned, 4-bank step -> <=2-way).
// Phase B: waves 0-3 = side 0 (xl), waves 4-7 = side 1 (xr); gemm2 with
//   B-fragments read from LDS. Drops the global h round-trip entirely.
__global__ __launch_bounds__(512) void CarbonGNN_36447092474498_gcngemm2(
    const unsigned short* __restrict__ xw, const int* __restrict__ off,
    const int* __restrict__ csr, const float* __restrict__ dinv,
    const float* __restrict__ bgcn,
    const unsigned short* __restrict__ wp,
    const float* __restrict__ bl, const float* __restrict__ br,
    const float* __restrict__ attw,
    unsigned short* __restrict__ xlr, float* __restrict__ S, int N){
  __shared__ unsigned short hsm[128 * 72];
  int t = threadIdx.x;
  int lane = t & 63;
  int w = t >> 6;                   // wave 0..7
  int r0 = blockIdx.x * 128;

  // ---- Phase A: GCN for 16 nodes per wave ----
  {
    int g = lane >> 3;              // edge slot 0..7
    int l8 = lane & 7;              // channel group
    int c8 = l8 * 8;
    for (int i = 0; i < 16; i++){
      int nl = w * 16 + i;          // local row 0..127 (wave-uniform)
      int node = r0 + nl;
      if (node < N){
        float di = dinv[node];
        float2v o2[4] = {{0.f,0.f},{0.f,0.f},{0.f,0.f},{0.f,0.f}};
        int k0 = off[node], k1 = off[node + 1];
        int k = k0;
        for (; k + 7 < k1; k += 8){
          int s = csr[k + g];
          uint4 v = *(const uint4*)(xw + (size_t)s * 64 + c8);
          float d = dinv[s];
          float2v D = {d, d};
          o2[0] = D * up2(v.x) + o2[0];
          o2[1] = D * up2(v.y) + o2[1];
          o2[2] = D * up2(v.z) + o2[2];
          o2[3] = D * up2(v.w) + o2[3];
        }
        if (k < k1){
          int kk = k + g;
          bool act = kk < k1;
          int s = csr[act ? kk : k0];
          uint4 v = *(const uint4*)(xw + (size_t)s * 64 + c8);
          float d = act ? dinv[s] : 0.f;
          float2v D = {d, d};
          o2[0] = D * up2(v.x) + o2[0];
          o2[1] = D * up2(v.y) + o2[1];
          o2[2] = D * up2(v.z) + o2[2];
          o2[3] = D * up2(v.w) + o2[3];
        }
        #pragma unroll
        for (int q = 0; q < 4; q++){
          o2[q].x += __shfl_xor(o2[q].x, 8, 64);  o2[q].y += __shfl_xor(o2[q].y, 8, 64);
          o2[q].x += __shfl_xor(o2[q].x, 16, 64); o2[q].y += __shfl_xor(o2[q].y, 16, 64);
          o2[q].x += __shfl_xor(o2[q].x, 32, 64); o2[q].y += __shfl_xor(o2[q].y, 32, 64);
        }
        uint4 su = *(const uint4*)(xw + (size_t)node * 64 + c8);
        float2v s01 = up2(su.x), s23 = up2(su.y), s45 = up2(su.z), s67 = up2(su.w);
        float4 bg0 = *(const float4*)(bgcn + c8);
        float4 bg1 = *(const float4*)(bgcn + c8 + 4);
        float v0 = fmaxf(fmaf(fmaf(s01.x, di, o2[0].x), di, bg0.x), 0.f);
        float v1 = fmaxf(fmaf(fmaf(s01.y, di, o2[0].y), di, bg0.y), 0.f);
        float v2 = fmaxf(fmaf(fmaf(s23.x, di, o2[1].x), di, bg0.z), 0.f);
        float v3 = fmaxf(fmaf(fmaf(s23.y, di, o2[1].y), di, bg0.w), 0.f);
        float v4 = fmaxf(fmaf(fmaf(s45.x, di, o2[2].x), di, bg1.x), 0.f);
        float v5 = fmaxf(fmaf(fmaf(s45.y, di, o2[2].y), di, bg1.y), 0.f);
        float v6 = fmaxf(fmaf(fmaf(s67.x, di, o2[3].x), di, bg1.z), 0.f);
        float v7 = fmaxf(fmaf(fmaf(s67.y, di, o2[3].y), di, bg1.w), 0.f);
        if (g == 0){
          unsigned int p01, p23, p45, p67;   // RNE pack, matches f2b
          asm("v_cvt_pk_bf16_f32 %0, %1, %2" : "=v"(p01) : "v"(v0), "v"(v1));
          asm("v_cvt_pk_bf16_f32 %0, %1, %2" : "=v"(p23) : "v"(v2), "v"(v3));
          asm("v_cvt_pk_bf16_f32 %0, %1, %2" : "=v"(p45) : "v"(v4), "v"(v5));
          asm("v_cvt_pk_bf16_f32 %0, %1, %2" : "=v"(p67) : "v"(v6), "v"(v7));
          uint4 hv; hv.x = p01; hv.y = p23; hv.z = p45; hv.w = p67;
          *(uint4*)(hsm + (size_t)nl * 72 + c8) = hv;
        }
      } else if (g == 0){
        uint4 zv; zv.x = 0; zv.y = 0; zv.z = 0; zv.w = 0;
        *(uint4*)(hsm + (size_t)nl * 72 + c8) = zv;
      }
    }
  }
  __syncthreads();

  // ---- Phase B: gemm2 from LDS ----
  int side = w >> 2;                // 0: xl cols, 1: xr cols
  int w4 = w & 3;
  int l15 = lane & 15;
  int lg = lane >> 4;
  int rbase = w4 * 32;
  int r0w = r0 + rbase;

  short8x bfr[2][2];
  #pragma unroll
  for (int rt = 0; rt < 2; rt++){
    int rl = rbase + rt * 16 + l15;
    const unsigned short* hp = hsm + (size_t)rl * 72 + lg * 8;
    bfr[rt][0] = *(const short8x*)(hp);
    bfr[rt][1] = *(const short8x*)(hp + 32);
  }

  const unsigned short* wpp = wp + (size_t)(side * 16) * 2048 + (size_t)lane * 8;
  short8x ah0 = *(const short8x*)(wpp);
  short8x al0 = *(const short8x*)(wpp + 512);
  short8x ah1 = *(const short8x*)(wpp + 1024);
  short8x al1 = *(const short8x*)(wpp + 1536);

  float sp0 = 0.f, sp1 = 0.f;
  for (int cl = 0; cl < 16; cl++){
    short8x ch0 = ah0, cg0 = al0, ch1 = ah1, cg1 = al1;
    if (cl < 15){
      const unsigned short* np = wpp + (size_t)(cl + 1) * 2048;
      ah0 = *(const short8x*)(np);
      al0 = *(const short8x*)(np + 512);
      ah1 = *(const short8x*)(np + 1024);
      al1 = *(const short8x*)(np + 1536);
    }
    int c4 = (side * 16 + cl) * 16 + lg * 4;
    float4 bias = (c4 < 256) ? *(const float4*)(bl + c4)
                             : *(const float4*)(br + (c4 - 256));
    float4 aw = *(const float4*)(attw + (c4 & 255));
    #pragma unroll
    for (int rt = 0; rt < 2; rt++){
      f32x4 acc = {0.f, 0.f, 0.f, 0.f};
      acc = __builtin_amdgcn_mfma_f32_16x16x32_bf16(ch0, bfr[rt][0], acc, 0, 0, 0);
      acc = __builtin_amdgcn_mfma_f32_16x16x32_bf16(cg0, bfr[rt][0], acc, 0, 0, 0);
      acc = __builtin_amdgcn_mfma_f32_16x16x32_bf16(ch1, bfr[rt][1], acc, 0, 0, 0);
      acc = __builtin_amdgcn_mfma_f32_16x16x32_bf16(cg1, bfr[rt][1], acc, 0, 0, 0);
      float v0 = acc[0] + bias.x;
      float v1 = acc[1] + bias.y;
      float v2 = acc[2] + bias.z;
      float v3 = acc[3] + bias.w;
      unsigned int p01, p23;                    // RNE pack, matches f2b
      asm("v_cvt_pk_bf16_f32 %0, %1, %2" : "=v"(p01) : "v"(v0), "v"(v1));
      asm("v_cvt_pk_bf16_f32 %0, %1, %2" : "=v"(p23) : "v"(v2), "v"(v3));
      int row = r0w + rt * 16 + l15;
      if (row < N){
        uint2 pv; pv.x = p01; pv.y = p23;
        *(uint2*)(xlr + (size_t)row * 512 + c4) = pv;
      }
      union { unsigned int u; float f; } q0, q1, q2, q3;
      q0.u = p01 << 16; q1.u = p01 & 0xffff0000u;
      q2.u = p23 << 16; q3.u = p23 & 0xffff0000u;
      float s = fmaf(aw.x, q0.f, fmaf(aw.y, q1.f, fmaf(aw.z, q2.f, aw.w * q3.f)));
      if (rt == 0) sp0 += s; else sp1 += s;
    }
    if ((cl & 3) == 3){
      int head = cl >> 2;
      float s0 = sp0, s1 = sp1;
      s0 += __shfl_xor(s0, 16, 64); s0 += __shfl_xor(s0, 32, 64);
      s1 += __shfl_xor(s1, 16, 64); s1 += __shfl_xor(s1, 32, 64);
      s0 *= 0.86561702453337803f;                // 0.6 * log2(e)
      s1 *= 0.86561702453337803f;
      if (lane < 16){
        int ra = r0w + l15;
        if (ra < N) S[(size_t)ra * 8 + side * 4 + head] = s0;
        int rb = r0w + 16 + l15;
        if (rb < N) S[(size_t)rb * 8 + side * 4 + head] = s1;
      }
      sp0 = 0.f; sp1 = 0.f;
    }
  }
}

// GATv2: exp2-domain anchored softmax; half-wave per edge, 4 edges/iter;
// depth-2 software pipeline of raw loads (csr idx + xl rows + S scalars)
// to hide gather latency under current-iteration compute.
__global__ __launch_bounds__(256) void CarbonGNN_36447092474498_kernel(
    const unsigned short* __restrict__ xlr, const int* __restrict__ off,
    const int* __restrict__ csr, const float* __restrict__ attw,
    const float* __restrict__ S,
    const float* __restrict__ bgat, const float* __restrict__ wlin,
    const float* __restrict__ blin, float* __restrict__ out, int N){
  const float c04 = 0.57707801635558535f;      // 0.4 * log2(e)
  int node = blockIdx.x * 4 + (threadIdx.x >> 6);
  if (node >= N) return;
  int lane = threadIdx.x & 63;
  int half = lane >> 5;
  int j = lane & 31;
  int hd = j >> 3;
  int c8 = j * 8;
  const unsigned short* xrow = xlr + (size_t)node * 512;

  uint4 xru = *(const uint4*)(xrow + 256 + c8);
  float2v xr2[4] = {up2(xru.x), up2(xru.y), up2(xru.z), up2(xru.w)};
  float aw[8];
  {
    float4 a0 = *(const float4*)(attw + c8);
    float4 a1 = *(const float4*)(attw + c8 + 4);
    aw[0] = a0.x; aw[1] = a0.y; aw[2] = a0.z; aw[3] = a0.w;
    aw[4] = a1.x; aw[5] = a1.y; aw[6] = a1.z; aw[7] = a1.w;
  }

  uint4 xsu = *(const uint4*)(xrow + c8);
  float2v xs2[4] = {up2(xsu.x), up2(xsu.y), up2(xsu.z), up2(xsu.w)};
  float Rs = 0.f;
  #pragma unroll
  for (int i = 0; i < 4; i++){
    float2v z = xs2[i] + xr2[i];
    Rs = fmaf(aw[2 * i],     fabsf(z.x), Rs);
    Rs = fmaf(aw[2 * i + 1], fabsf(z.y), Rs);
  }
  Rs = red8(Rs);
  float base = -fmaf(c04, Rs, S[(size_t)node * 8 + hd]);

  float denom;
  float2v o2[4];
  if (half == 0){
    denom = 1.f;
    #pragma unroll
    for (int i = 0; i < 4; i++) o2[i] = xs2[i];
  } else {
    denom = 0.f;
    #pragma unroll
    for (int i = 0; i < 4; i++) o2[i] = (float2v){0.f, 0.f};
  }

  int k0 = off[node], k1 = off[node + 1];
  int k = k0;
  uint4 v0, v1;
  float Sl0, Sl1;
  bool have = (k + 3 < k1);
  if (have){
    int i0 = csr[k + half];
    int i1 = csr[k + 2 + half];
    v0 = *(const uint4*)(xlr + (size_t)i0 * 512 + c8);
    v1 = *(const uint4*)(xlr + (size_t)i1 * 512 + c8);
    Sl0 = S[(size_t)i0 * 8 + hd];
    Sl1 = S[(size_t)i1 * 8 + hd];
  }
  while (have){
    uint4 cv0 = v0, cv1 = v1;
    float cS0 = Sl0, cS1 = Sl1;
    k += 4;
    have = (k + 3 < k1);
    if (have){                         // prefetch next iteration's raw data
      int i0 = csr[k + half];
      int i1 = csr[k + 2 + half];
      v0 = *(const uint4*)(xlr + (size_t)i0 * 512 + c8);
      v1 = *(const uint4*)(xlr + (size_t)i1 * 512 + c8);
      Sl0 = S[(size_t)i0 * 8 + hd];
      Sl1 = S[(size_t)i1 * 8 + hd];
    }
    float2v a0[4] = {up2(cv0.x), up2(cv0.y), up2(cv0.z), up2(cv0.w)};
    float2v a1[4] = {up2(cv1.x), up2(cv1.y), up2(cv1.z), up2(cv1.w)};
    float R0 = 0.f, R1 = 0.f;
    #pragma unroll
    for (int i = 0; i < 4; i++){
      float2v z0 = a0[i] + xr2[i];
      float2v z1 = a1[i] + xr2[i];
      float w0 = aw[2 * i], w1 = aw[2 * i + 1];
      R0 = fmaf(w0, fabsf(z0.x), R0); R0 = fmaf(w1, fabsf(z0.y), R0);
      R1 = fmaf(w0, fabsf(z1.x), R1); R1 = fmaf(w1, fabsf(z1.y), R1);
    }
    R0 = red8(R0);
    R1 = red8(R1);
    float e0 = exp2f(fmaf(c04, R0, cS0 + base));
    float e1 = exp2f(fmaf(c04, R1, cS1 + base));
    denom += e0 + e1;
    float2v E0 = {e0, e0}, E1 = {e1, e1};
    #pragma unroll
    for (int i = 0; i < 4; i++){
      o2[i] = E0 * a0[i] + o2[i];
      o2[i] = E1 * a1[i] + o2[i];
    }
  }
  for (; k < k1; k += 2){                // masked tail
    int kk = k + half;
    bool act = kk < k1;
    int s = csr[act ? kk : k];
    uint4 v = *(const uint4*)(xlr + (size_t)s * 512 + c8);
    float Sl = S[(size_t)s * 8 + hd];
    float2v a[4] = {up2(v.x), up2(v.y), up2(v.z), up2(v.w)};
    float Rr = 0.f;
    #pragma unroll
    for (int i = 0; i < 4; i++){
      float2v z = a[i] + xr2[i];
      Rr = fmaf(aw[2 * i],     fabsf(z.x), Rr);
      Rr = fmaf(aw[2 * i + 1], fabsf(z.y), Rr);
    }
    Rr = red8(Rr);
    float e = act ? exp2f(fmaf(c04, Rr, Sl + base)) : 0.f;
    denom += e;
    float2v E = {e, e};
    #pragma unroll
    for (int i = 0; i < 4; i++) o2[i] = E * a[i] + o2[i];
  }

  denom += __shfl_xor(denom, 32, 64);
  #pragma unroll
  for (int i = 0; i < 4; i++){
    o2[i].x += __shfl_xor(o2[i].x, 32, 64);
    o2[i].y += __shfl_xor(o2[i].y, 32, 64);
  }
  float inv = 1.f / denom;
  float2v I = {inv, inv};
  #pragma unroll
  for (int i = 0; i < 4; i++) o2[i] = o2[i] * I;
  #pragma unroll
  for (int i = 0; i < 4; i++){
    o2[i].x += __shfl_xor(o2[i].x, 8, 64);  o2[i].y += __shfl_xor(o2[i].y, 8, 64);
    o2[i].x += __shfl_xor(o2[i].x, 16, 64); o2[i].y += __shfl_xor(o2[i].y, 16, 64);
  }
  int cb = (j & 7) * 8;
  float4 bg0 = *(const float4*)(bgat + cb);
  float4 bg1 = *(const float4*)(bgat + cb + 4);
  float4 wl0 = *(const float4*)(wlin + cb);
  float4 wl1 = *(const float4*)(wlin + cb + 4);
  float ov[8]  = {o2[0].x, o2[0].y, o2[1].x, o2[1].y, o2[2].x, o2[2].y, o2[3].x, o2[3].y};
  float bgv[8] = {bg0.x, bg0.y, bg0.z, bg0.w, bg1.x, bg1.y, bg1.z, bg1.w};
  float wlv[8] = {wl0.x, wl0.y, wl0.z, wl0.w, wl1.x, wl1.y, wl1.z, wl1.w};
  float r = 0.f;
  #pragma unroll
  for (int i = 0; i < 8; i++){
    float g = fmaxf(fmaf(ov[i], 0.25f, bgv[i]), 0.f);
    r = fmaf(g, wlv[i], r);
  }
  r = red8(r);
  if (lane == 0) out[node] = r + blin[0];
}

extern "C" void kernel_launch(void* const* d_in, const int* in_sizes, int n_in,
                              void* d_out, int out_size, void* d_ws, size_t ws_size,
                              hipStream_t stream){
  const float* x    = (const float*)d_in[0];
  const int* edge_index = (const int*)d_in[1];
  const float* Wg   = (const float*)d_in[3];
  const float* bgcn = (const float*)d_in[4];
  const float* Wl   = (const float*)d_in[5];
  const float* bl   = (const float*)d_in[6];
  const float* Wr   = (const float*)d_in[7];
  const float* br   = (const float*)d_in[8];
  const float* attw = (const float*)d_in[9];
  const float* bgat = (const float*)d_in[10];
  const float* wlin = (const float*)d_in[11];
  const float* blin = (const float*)d_in[12];
  float* out = (float*)d_out;

  const int N = in_sizes[0] / 128;
  const int E = in_sizes[1] / 2;
  const int* srcv = edge_index;
  const int* dstv = edge_index + E;

  char* w = (char*)d_ws;
  size_t o = 0;
  int* cnt = (int*)(w + o);            o += (((size_t)N * 4) + 255) & ~(size_t)255;
  int* cursor = (int*)(w + o);         o += (((size_t)N * 4) + 255) & ~(size_t)255;
  int* excl = (int*)(w + o);           o += (((size_t)N * 4) + 255) & ~(size_t)255;
  int* off = (int*)(w + o);            o += (((size_t)(N + 1) * 4) + 255) & ~(size_t)255;
  int* bsum = (int*)(w + o);           o += (2048 * 4 + 255) & ~(size_t)255;
  float* dinv = (float*)(w + o);       o += (((size_t)N * 4) + 255) & ~(size_t)255;
  float* S = (float*)(w + o);          o += (((size_t)N * 8 * 4) + 255) & ~(size_t)255;
  unsigned short* xw = (unsigned short*)(w + o);   o += (((size_t)N * 64 * 2) + 255) & ~(size_t)255;
  unsigned short* xlr = (unsigned short*)(w + o);  o += (((size_t)N * 512 * 2) + 255) & ~(size_t)255;
  int* csr = (int*)(w + o);            o += (((size_t)E * 4) + 255) & ~(size_t)255;
  unsigned short* wp = (unsigned short*)(w + o);   o += (size_t)131072;  // 64x512 x {hi,lo}
  unsigned short* wp1 = (unsigned short*)(w + o);  o += (size_t)32768;   // 128x64 x {hi,lo}
  (void)o; (void)ws_size; (void)n_in; (void)out_size;

  const int nbN = (N + 255) / 256;
  const int nbE = (E + 255) / 256;
  const int nb4 = (N + 3) / 4;
  const int nb64 = (N + 63) / 64;
  const int nb128 = (N + 127) / 128;

  CarbonGNN_36447092474498_initpack<<<nbN + 320, 256, 0, stream>>>(
      cnt, cursor, N, nbN, Wg, Wl, Wr, wp1, wp);
  CarbonGNN_36447092474498_histgemm1<<<nbE + nb64, 256, 0, stream>>>(
      dstv, E, cnt, nbE, x, wp1, xw, N);
  CarbonGNN_36447092474498_scan1<<<nbN, 256, 0, stream>>>(cnt, N, excl, bsum);
  CarbonGNN_36447092474498_scan3<<<nbN, 256, 0, stream>>>(excl, bsum, nbN, cnt, N, E, off, dinv);
  CarbonGNN_36447092474498_fill <<<nbE, 256, 0, stream>>>(srcv, dstv, E, off, cursor, csr);
  CarbonGNN_36447092474498_gcngemm2<<<nb128, 512, 0, stream>>>(
      xw, off, csr, dinv, bgcn, wp, bl, br, attw, xlr, S, N);
  CarbonGNN_36447092474498_kernel<<<nb4, 256, 0, stream>>>(xlr, off, csr, attw, S, bgat, wlin, blin, out, N);
}

// Round 8
// 312.723 us; speedup vs baseline: 1.0333x; 1.0333x over previous
//
#include <hip/hip_runtime.h>

static __device__ inline float b2f(unsigned short u){
  union { unsigned int i; float f; } v; v.i = ((unsigned int)u) << 16; return v.f;
}
static __device__ inline unsigned short f2b(float f){
  union { float ff; unsigned int u; } v; v.ff = f;
  unsigned int xx = v.u;
  return (unsigned short)((xx + 0x7fffu + ((xx >> 16) & 1u)) >> 16);
}

typedef __attribute__((ext_vector_type(8))) short short8x;   // 8 bf16 (4 VGPRs)
typedef __attribute__((ext_vector_type(4))) float f32x4;
typedef __attribute__((ext_vector_type(2))) float float2v;   // -> v_pk_*_f32

// unpack one dword holding 2 bf16 -> float2 {lo, hi}
static __device__ inline float2v up2(unsigned int u){
  union { unsigned int i; float f; } a, b;
  a.i = u << 16; b.i = u & 0xffff0000u;
  float2v r; r.x = a.f; r.y = b.f; return r;
}

// 8-lane sum via DPP (VALU-only). Requires whole wave active (wave-uniform guards).
#define DPPADD(x, ctrl) \
  ((x) + __int_as_float(__builtin_amdgcn_update_dpp(0, __float_as_int(x), (ctrl), 0xf, 0xf, true)))
static __device__ inline float red8(float x){
  x = DPPADD(x, 0xb1);    // quad_perm [1,0,3,2]
  x = DPPADD(x, 0x4e);    // quad_perm [2,3,0,1]
  x = DPPADD(x, 0x141);   // row_half_mirror
  return x;
}

// ---------------- shared phase bodies ----------------

// Wg^T pack item (idx in [0,16384))
static __device__ inline void dev_wpack1_item(int idx, const float* __restrict__ Wg,
                                              unsigned short* __restrict__ wp1){
  int i    = idx & 7;
  int lane = (idx >> 3) & 63;
  int p    = (idx >> 9) & 1;
  int kt   = (idx >> 10) & 3;
  int ct   = idx >> 12;                            // 0..3
  int c = ct * 16 + (lane & 15);
  int k = kt * 32 + (lane >> 4) * 8 + i;
  float w = Wg[k * 64 + c];
  unsigned short hi = f2b(w);
  unsigned short outv = p ? f2b(w - b2f(hi)) : hi;
  int fb = ct * 8 + kt * 2 + p;
  wp1[(size_t)fb * 512 + lane * 8 + i] = outv;
}

// [Wl|Wr]^T pack item (idx in [0,65536))
static __device__ inline void dev_wpack2_item(int idx, const float* __restrict__ Wl,
                                              const float* __restrict__ Wr,
                                              unsigned short* __restrict__ wp){
  int i    = idx & 7;
  int lane = (idx >> 3) & 63;
  int p    = (idx >> 9) & 1;
  int kt   = (idx >> 10) & 1;
  int ct   = idx >> 11;                            // 0..31
  int c = ct * 16 + (lane & 15);
  int k = kt * 32 + (lane >> 4) * 8 + i;
  float w = (c < 256) ? Wl[k * 256 + c] : Wr[k * 256 + (c - 256)];
  unsigned short hi = f2b(w);
  unsigned short outv = p ? f2b(w - b2f(hi)) : hi;
  int fb = ct * 4 + kt * 2 + p;
  wp[(size_t)fb * 512 + lane * 8 + i] = outv;
}

// gemm1: virtual block vb covers 64 rows. D' = Wg^T . x^T via 16x16x32 MFMA.
static __device__ inline void dev_gemm1(int vb, int t, const float* __restrict__ x,
                                        const unsigned short* __restrict__ wp1,
                                        unsigned short* __restrict__ xw, int N){
  int lane = t & 63;
  int l15 = lane & 15;
  int lg = lane >> 4;
  int row = vb * 64 + (t >> 6) * 16 + l15;
  int rc = row < N ? row : N - 1;
  const float* xp = x + (size_t)rc * 128 + lg * 8;

  short8x xh[4], xlo[4];
  #pragma unroll
  for (int kt = 0; kt < 4; kt++){
    float4 a = *(const float4*)(xp + kt * 32);
    float4 b = *(const float4*)(xp + kt * 32 + 4);
    unsigned int h0, h1, h2, h3;
    asm("v_cvt_pk_bf16_f32 %0, %1, %2" : "=v"(h0) : "v"(a.x), "v"(a.y));
    asm("v_cvt_pk_bf16_f32 %0, %1, %2" : "=v"(h1) : "v"(a.z), "v"(a.w));
    asm("v_cvt_pk_bf16_f32 %0, %1, %2" : "=v"(h2) : "v"(b.x), "v"(b.y));
    asm("v_cvt_pk_bf16_f32 %0, %1, %2" : "=v"(h3) : "v"(b.z), "v"(b.w));
    union { unsigned int u[4]; short8x v; } H;
    H.u[0] = h0; H.u[1] = h1; H.u[2] = h2; H.u[3] = h3;
    xh[kt] = H.v;
    union { unsigned int u; float ff; } q;
    float r0, r1, r2, r3, r4, r5, r6, r7;
    q.u = h0 << 16;          r0 = a.x - q.ff;
    q.u = h0 & 0xffff0000u;  r1 = a.y - q.ff;
    q.u = h1 << 16;          r2 = a.z - q.ff;
    q.u = h1 & 0xffff0000u;  r3 = a.w - q.ff;
    q.u = h2 << 16;          r4 = b.x - q.ff;
    q.u = h2 & 0xffff0000u;  r5 = b.y - q.ff;
    q.u = h3 << 16;          r6 = b.z - q.ff;
    q.u = h3 & 0xffff0000u;  r7 = b.w - q.ff;
    unsigned int l0, l1, l2, l3;
    asm("v_cvt_pk_bf16_f32 %0, %1, %2" : "=v"(l0) : "v"(r0), "v"(r1));
    asm("v_cvt_pk_bf16_f32 %0, %1, %2" : "=v"(l1) : "v"(r2), "v"(r3));
    asm("v_cvt_pk_bf16_f32 %0, %1, %2" : "=v"(l2) : "v"(r4), "v"(r5));
    asm("v_cvt_pk_bf16_f32 %0, %1, %2" : "=v"(l3) : "v"(r6), "v"(r7));
    union { unsigned int u[4]; short8x v; } L;
    L.u[0] = l0; L.u[1] = l1; L.u[2] = l2; L.u[3] = l3;
    xlo[kt] = L.v;
  }

  #pragma unroll
  for (int ct = 0; ct < 4; ct++){
    f32x4 acc = {0.f, 0.f, 0.f, 0.f};
    #pragma unroll
    for (int kt = 0; kt < 4; kt++){
      const unsigned short* ap = wp1 + (size_t)(ct * 8 + kt * 2) * 512 + (size_t)lane * 8;
      short8x wh = *(const short8x*)(ap);
      short8x wl = *(const short8x*)(ap + 512);
      acc = __builtin_amdgcn_mfma_f32_16x16x32_bf16(wh, xh[kt], acc, 0, 0, 0);
      acc = __builtin_amdgcn_mfma_f32_16x16x32_bf16(wl, xh[kt], acc, 0, 0, 0);
      acc = __builtin_amdgcn_mfma_f32_16x16x32_bf16(wh, xlo[kt], acc, 0, 0, 0);
    }
    unsigned int p01, p23;
    asm("v_cvt_pk_bf16_f32 %0, %1, %2" : "=v"(p01) : "v"(acc[0]), "v"(acc[1]));
    asm("v_cvt_pk_bf16_f32 %0, %1, %2" : "=v"(p23) : "v"(acc[2]), "v"(acc[3]));
    if (row < N){
      uint2 pv; pv.x = p01; pv.y = p23;
      *(uint2*)(xw + (size_t)row * 64 + ct * 16 + lg * 4) = pv;
    }
  }
}

// ---------------- kernels (8 dispatches) ----------------

// init (zero cnt/cursor) + weight packing, disjoint block ranges
__global__ __launch_bounds__(256) void CarbonGNN_36447092474498_initpack(
    int* __restrict__ cnt, int* __restrict__ cursor, int N, int nbN,
    const float* __restrict__ Wg, const float* __restrict__ Wl,
    const float* __restrict__ Wr,
    unsigned short* __restrict__ wp1, unsigned short* __restrict__ wp){
  int b = blockIdx.x;
  if (b < nbN){
    int i = b * 256 + threadIdx.x;
    if (i < N){ cnt[i] = 0; cursor[i] = 0; }
  } else if (b < nbN + 64){
    dev_wpack1_item((b - nbN) * 256 + threadIdx.x, Wg, wp1);
  } else {
    dev_wpack2_item((b - nbN - 64) * 256 + threadIdx.x, Wl, Wr, wp);
  }
}

// degree histogram + gemm1 (independent), disjoint block ranges
__global__ __launch_bounds__(256) void CarbonGNN_36447092474498_histgemm1(
    const int* __restrict__ dst, int E, int* __restrict__ cnt, int nbE,
    const float* __restrict__ x, const unsigned short* __restrict__ wp1,
    unsigned short* __restrict__ xw, int N){
  int b = blockIdx.x;
  if (b < nbE){
    int e = b * 256 + threadIdx.x;
    if (e < E) atomicAdd(&cnt[dst[e]], 1);
  } else {
    dev_gemm1(b - nbE, threadIdx.x, x, wp1, xw, N);
  }
}

__global__ __launch_bounds__(256) void CarbonGNN_36447092474498_scan1(
    const int* __restrict__ cnt, int n, int* __restrict__ excl, int* __restrict__ bsum){
  __shared__ int sm[256];
  int t = threadIdx.x;
  int i = blockIdx.x * 256 + t;
  int v = (i < n) ? cnt[i] : 0;
  sm[t] = v;
  __syncthreads();
  for (int ofs = 1; ofs < 256; ofs <<= 1){
    int y = (t >= ofs) ? sm[t - ofs] : 0;
    __syncthreads();
    sm[t] += y;
    __syncthreads();
  }
  if (i < n) excl[i] = sm[t] - v;
  if (t == 255) bsum[blockIdx.x] = sm[t];
}

__global__ __launch_bounds__(256) void CarbonGNN_36447092474498_scan3(
    const int* __restrict__ excl, const int* __restrict__ bsum, int nb,
    const int* __restrict__ cnt, int n, int E,
    int* __restrict__ off, float* __restrict__ dinv){
  __shared__ int sm[256];
  int t = threadIdx.x;
  int v = (t < nb) ? bsum[t] : 0;
  sm[t] = v;
  __syncthreads();
  for (int ofs = 1; ofs < 256; ofs <<= 1){
    int y = (t >= ofs) ? sm[t - ofs] : 0;
    __syncthreads();
    sm[t] += y;
    __syncthreads();
  }
  int bofs = (blockIdx.x == 0) ? 0 : sm[blockIdx.x - 1];
  int i = blockIdx.x * 256 + t;
  if (i < n){
    off[i] = excl[i] + bofs;
    int c = cnt[i];
    dinv[i] = (c >= 0 && c <= E) ? rsqrtf((float)(c + 1)) : 1.0f;
  }
  if (i == 0) off[n] = E;
}

__global__ __launch_bounds__(256) void CarbonGNN_36447092474498_fill(
    const int* __restrict__ src, const int* __restrict__ dst, int E,
    const int* __restrict__ off, int* __restrict__ cursor, int* __restrict__ csr){
  int e = blockIdx.x * 256 + threadIdx.x;
  if (e < E){
    int d = dst[e];
    int p = atomicAdd(&cursor[d], 1);
    csr[off[d] + p] = src[e];
  }
}

// GCN aggregate: eighth-wave per edge — 8 lanes x 8 channels (one uint4/lane),
// 8 edges in flight per wave; combine groups with 3 shfl levels. (R6 proven.)
__global__ __launch_bounds__(256) void CarbonGNN_36447092474498_gcn(
    const unsigned short* __restrict__ xw, const int* __restrict__ off,
    const int* __restrict__ csr, const float* __restrict__ dinv,
    const float* __restrict__ bgcn, unsigned short* __restrict__ h, int N){
  int node = blockIdx.x * 4 + (threadIdx.x >> 6);
  if (node >= N) return;
  int lane = threadIdx.x & 63;
  int g = lane >> 3;           // edge slot 0..7
  int l8 = lane & 7;           // channel group
  int c8 = l8 * 8;
  float di = dinv[node];
  float2v o2[4] = {{0.f,0.f},{0.f,0.f},{0.f,0.f},{0.f,0.f}};
  int k0 = off[node], k1 = off[node + 1];
  int k = k0;
  for (; k + 7 < k1; k += 8){            // 8 edges per iter, 1 per group
    int s = csr[k + g];
    uint4 v = *(const uint4*)(xw + (size_t)s * 64 + c8);
    float d = dinv[s];
    float2v D = {d, d};
    o2[0] = D * up2(v.x) + o2[0];
    o2[1] = D * up2(v.y) + o2[1];
    o2[2] = D * up2(v.z) + o2[2];
    o2[3] = D * up2(v.w) + o2[3];
  }
  if (k < k1){                           // masked tail (<= 7 edges)
    int kk = k + g;
    bool act = kk < k1;
    int s = csr[act ? kk : k0];
    uint4 v = *(const uint4*)(xw + (size_t)s * 64 + c8);
    float d = act ? dinv[s] : 0.f;
    float2v D = {d, d};
    o2[0] = D * up2(v.x) + o2[0];
    o2[1] = D * up2(v.y) + o2[1];
    o2[2] = D * up2(v.z) + o2[2];
    o2[3] = D * up2(v.w) + o2[3];
  }
  // combine the 8 edge-groups (lanes with equal l8)
  #pragma unroll
  for (int i = 0; i < 4; i++){
    o2[i].x += __shfl_xor(o2[i].x, 8, 64);  o2[i].y += __shfl_xor(o2[i].y, 8, 64);
    o2[i].x += __shfl_xor(o2[i].x, 16, 64); o2[i].y += __shfl_xor(o2[i].y, 16, 64);
    o2[i].x += __shfl_xor(o2[i].x, 32, 64); o2[i].y += __shfl_xor(o2[i].y, 32, 64);
  }
  // self + bias + relu; group 0 writes
  uint4 su = *(const uint4*)(xw + (size_t)node * 64 + c8);
  float2v s01 = up2(su.x), s23 = up2(su.y), s45 = up2(su.z), s67 = up2(su.w);
  float4 bg0 = *(const float4*)(bgcn + c8);
  float4 bg1 = *(const float4*)(bgcn + c8 + 4);
  float v0 = fmaxf(fmaf(fmaf(s01.x, di, o2[0].x), di, bg0.x), 0.f);
  float v1 = fmaxf(fmaf(fmaf(s01.y, di, o2[0].y), di, bg0.y), 0.f);
  float v2 = fmaxf(fmaf(fmaf(s23.x, di, o2[1].x), di, bg0.z), 0.f);
  float v3 = fmaxf(fmaf(fmaf(s23.y, di, o2[1].y), di, bg0.w), 0.f);
  float v4 = fmaxf(fmaf(fmaf(s45.x, di, o2[2].x), di, bg1.x), 0.f);
  float v5 = fmaxf(fmaf(fmaf(s45.y, di, o2[2].y), di, bg1.y), 0.f);
  float v6 = fmaxf(fmaf(fmaf(s67.x, di, o2[3].x), di, bg1.z), 0.f);
  float v7 = fmaxf(fmaf(fmaf(s67.y, di, o2[3].y), di, bg1.w), 0.f);
  if (g == 0){
    unsigned int p01, p23, p45, p67;   // RNE pack, matches f2b
    asm("v_cvt_pk_bf16_f32 %0, %1, %2" : "=v"(p01) : "v"(v0), "v"(v1));
    asm("v_cvt_pk_bf16_f32 %0, %1, %2" : "=v"(p23) : "v"(v2), "v"(v3));
    asm("v_cvt_pk_bf16_f32 %0, %1, %2" : "=v"(p45) : "v"(v4), "v"(v5));
    asm("v_cvt_pk_bf16_f32 %0, %1, %2" : "=v"(p67) : "v"(v6), "v"(v7));
    uint4 hv; hv.x = p01; hv.y = p23; hv.z = p45; hv.w = p67;
    *(uint4*)(h + (size_t)node * 64 + c8) = hv;
  }
}

// gemm2 (MFMA): xlr[N,512] = h[N,64] @ [Wl|Wr][64,512] + b, bf16 out, plus
// S'[n][side*4+head] = 0.6*log2(e) * att_head . rounded(x_side[n, ...]).
__global__ __launch_bounds__(256) void CarbonGNN_36447092474498_gemm2(
    const unsigned short* __restrict__ h, const unsigned short* __restrict__ wp,
    const float* __restrict__ bl, const float* __restrict__ br,
    const float* __restrict__ attw,
    unsigned short* __restrict__ xlr, float* __restrict__ S, int N){
  int t = threadIdx.x;
  int lane = t & 63;
  int l15 = lane & 15;
  int lg = lane >> 4;
  int r0 = blockIdx.x * 128 + (t >> 6) * 32;
  int side = blockIdx.y;                 // 0: xl cols 0..255, 1: xr cols 256..511

  short8x bfr[2][2];
  #pragma unroll
  for (int rt = 0; rt < 2; rt++){
    int row = r0 + rt * 16 + l15;
    int rc = row < N ? row : (N - 1);
    const unsigned short* hp = h + (size_t)rc * 64 + lg * 8;
    bfr[rt][0] = *(const short8x*)(hp);
    bfr[rt][1] = *(const short8x*)(hp + 32);
  }

  const unsigned short* wpp = wp + (size_t)(side * 16) * 2048 + (size_t)lane * 8;
  short8x ah0 = *(const short8x*)(wpp);
  short8x al0 = *(const short8x*)(wpp + 512);
  short8x ah1 = *(const short8x*)(wpp + 1024);
  short8x al1 = *(const short8x*)(wpp + 1536);

  float sp0 = 0.f, sp1 = 0.f;
  for (int cl = 0; cl < 16; cl++){
    short8x ch0 = ah0, cg0 = al0, ch1 = ah1, cg1 = al1;
    if (cl < 15){
      const unsigned short* np = wpp + (size_t)(cl + 1) * 2048;
      ah0 = *(const short8x*)(np);
      al0 = *(const short8x*)(np + 512);
      ah1 = *(const short8x*)(np + 1024);
      al1 = *(const short8x*)(np + 1536);
    }
    int c4 = (side * 16 + cl) * 16 + lg * 4;
    float4 bias = (c4 < 256) ? *(const float4*)(bl + c4)
                             : *(const float4*)(br + (c4 - 256));
    float4 aw = *(const float4*)(attw + (c4 & 255));
    #pragma unroll
    for (int rt = 0; rt < 2; rt++){
      f32x4 acc = {0.f, 0.f, 0.f, 0.f};
      acc = __builtin_amdgcn_mfma_f32_16x16x32_bf16(ch0, bfr[rt][0], acc, 0, 0, 0);
      acc = __builtin_amdgcn_mfma_f32_16x16x32_bf16(cg0, bfr[rt][0], acc, 0, 0, 0);
      acc = __builtin_amdgcn_mfma_f32_16x16x32_bf16(ch1, bfr[rt][1], acc, 0, 0, 0);
      acc = __builtin_amdgcn_mfma_f32_16x16x32_bf16(cg1, bfr[rt][1], acc, 0, 0, 0);
      float v0 = acc[0] + bias.x;
      float v1 = acc[1] + bias.y;
      float v2 = acc[2] + bias.z;
      float v3 = acc[3] + bias.w;
      unsigned int p01, p23;                    // RNE pack, matches f2b
      asm("v_cvt_pk_bf16_f32 %0, %1, %2" : "=v"(p01) : "v"(v0), "v"(v1));
      asm("v_cvt_pk_bf16_f32 %0, %1, %2" : "=v"(p23) : "v"(v2), "v"(v3));
      int row = r0 + rt * 16 + l15;
      if (row < N){
        uint2 pv; pv.x = p01; pv.y = p23;
        *(uint2*)(xlr + (size_t)row * 512 + c4) = pv;
      }
      union { unsigned int u; float f; } q0, q1, q2, q3;
      q0.u = p01 << 16; q1.u = p01 & 0xffff0000u;
      q2.u = p23 << 16; q3.u = p23 & 0xffff0000u;
      float s = fmaf(aw.x, q0.f, fmaf(aw.y, q1.f, fmaf(aw.z, q2.f, aw.w * q3.f)));
      if (rt == 0) sp0 += s; else sp1 += s;
    }
    if ((cl & 3) == 3){
      int head = cl >> 2;
      float s0 = sp0, s1 = sp1;
      s0 += __shfl_xor(s0, 16, 64); s0 += __shfl_xor(s0, 32, 64);
      s1 += __shfl_xor(s1, 16, 64); s1 += __shfl_xor(s1, 32, 64);
      s0 *= 0.86561702453337803f;                // 0.6 * log2(e)
      s1 *= 0.86561702453337803f;
      if (lane < 16){
        int ra = r0 + l15;
        if (ra < N) S[(size_t)ra * 8 + side * 4 + head] = s0;
        int rb = r0 + 16 + l15;
        if (rb < N) S[(size_t)rb * 8 + side * 4 + head] = s1;
      }
      sp0 = 0.f; sp1 = 0.f;
    }
  }
}

// GATv2: exp2-domain anchored softmax; half-wave per edge, 4 edges/iter;
// depth-2 software pipeline of raw loads (csr idx + xl rows + S scalars).
__global__ __launch_bounds__(256) void CarbonGNN_36447092474498_kernel(
    const unsigned short* __restrict__ xlr, const int* __restrict__ off,
    const int* __restrict__ csr, const float* __restrict__ attw,
    const float* __restrict__ S,
    const float* __restrict__ bgat, const float* __restrict__ wlin,
    const float* __restrict__ blin, float* __restrict__ out, int N){
  const float c04 = 0.57707801635558535f;      // 0.4 * log2(e)
  int node = blockIdx.x * 4 + (threadIdx.x >> 6);
  if (node >= N) return;
  int lane = threadIdx.x & 63;
  int half = lane >> 5;
  int j = lane & 31;
  int hd = j >> 3;
  int c8 = j * 8;
  const unsigned short* xrow = xlr + (size_t)node * 512;

  uint4 xru = *(const uint4*)(xrow + 256 + c8);
  float2v xr2[4] = {up2(xru.x), up2(xru.y), up2(xru.z), up2(xru.w)};
  float aw[8];
  {
    float4 a0 = *(const float4*)(attw + c8);
    float4 a1 = *(const float4*)(attw + c8 + 4);
    aw[0] = a0.x; aw[1] = a0.y; aw[2] = a0.z; aw[3] = a0.w;
    aw[4] = a1.x; aw[5] = a1.y; aw[6] = a1.z; aw[7] = a1.w;
  }

  uint4 xsu = *(const uint4*)(xrow + c8);
  float2v xs2[4] = {up2(xsu.x), up2(xsu.y), up2(xsu.z), up2(xsu.w)};
  float Rs = 0.f;
  #pragma unroll
  for (int i = 0; i < 4; i++){
    float2v z = xs2[i] + xr2[i];
    Rs = fmaf(aw[2 * i],     fabsf(z.x), Rs);
    Rs = fmaf(aw[2 * i + 1], fabsf(z.y), Rs);
  }
  Rs = red8(Rs);
  float base = -fmaf(c04, Rs, S[(size_t)node * 8 + hd]);

  float denom;
  float2v o2[4];
  if (half == 0){
    denom = 1.f;
    #pragma unroll
    for (int i = 0; i < 4; i++) o2[i] = xs2[i];
  } else {
    denom = 0.f;
    #pragma unroll
    for (int i = 0; i < 4; i++) o2[i] = (float2v){0.f, 0.f};
  }

  int k0 = off[node], k1 = off[node + 1];
  int k = k0;
  uint4 v0, v1;
  float Sl0, Sl1;
  bool have = (k + 3 < k1);
  if (have){
    int i0 = csr[k + half];
    int i1 = csr[k + 2 + half];
    v0 = *(const uint4*)(xlr + (size_t)i0 * 512 + c8);
    v1 = *(const uint4*)(xlr + (size_t)i1 * 512 + c8);
    Sl0 = S[(size_t)i0 * 8 + hd];
    Sl1 = S[(size_t)i1 * 8 + hd];
  }
  while (have){
    uint4 cv0 = v0, cv1 = v1;
    float cS0 = Sl0, cS1 = Sl1;
    k += 4;
    have = (k + 3 < k1);
    if (have){                         // prefetch next iteration's raw data
      int i0 = csr[k + half];
      int i1 = csr[k + 2 + half];
      v0 = *(const uint4*)(xlr + (size_t)i0 * 512 + c8);
      v1 = *(const uint4*)(xlr + (size_t)i1 * 512 + c8);
      Sl0 = S[(size_t)i0 * 8 + hd];
      Sl1 = S[(size_t)i1 * 8 + hd];
    }
    float2v a0[4] = {up2(cv0.x), up2(cv0.y), up2(cv0.z), up2(cv0.w)};
    float2v a1[4] = {up2(cv1.x), up2(cv1.y), up2(cv1.z), up2(cv1.w)};
    float R0 = 0.f, R1 = 0.f;
    #pragma unroll
    for (int i = 0; i < 4; i++){
      float2v z0 = a0[i] + xr2[i];
      float2v z1 = a1[i] + xr2[i];
      float w0 = aw[2 * i], w1 = aw[2 * i + 1];
      R0 = fmaf(w0, fabsf(z0.x), R0); R0 = fmaf(w1, fabsf(z0.y), R0);
      R1 = fmaf(w0, fabsf(z1.x), R1); R1 = fmaf(w1, fabsf(z1.y), R1);
    }
    R0 = red8(R0);
    R1 = red8(R1);
    float e0 = exp2f(fmaf(c04, R0, cS0 + base));
    float e1 = exp2f(fmaf(c04, R1, cS1 + base));
    denom += e0 + e1;
    float2v E0 = {e0, e0}, E1 = {e1, e1};
    #pragma unroll
    for (int i = 0; i < 4; i++){
      o2[i] = E0 * a0[i] + o2[i];
      o2[i] = E1 * a1[i] + o2[i];
    }
  }
  for (; k < k1; k += 2){                // masked tail
    int kk = k + half;
    bool act = kk < k1;
    int s = csr[act ? kk : k];
    uint4 v = *(const uint4*)(xlr + (size_t)s * 512 + c8);
    float Sl = S[(size_t)s * 8 + hd];
    float2v a[4] = {up2(v.x), up2(v.y), up2(v.z), up2(v.w)};
    float Rr = 0.f;
    #pragma unroll
    for (int i = 0; i < 4; i++){
      float2v z = a[i] + xr2[i];
      Rr = fmaf(aw[2 * i],     fabsf(z.x), Rr);
      Rr = fmaf(aw[2 * i + 1], fabsf(z.y), Rr);
    }
    Rr = red8(Rr);
    float e = act ? exp2f(fmaf(c04, Rr, Sl + base)) : 0.f;
    denom += e;
    float2v E = {e, e};
    #pragma unroll
    for (int i = 0; i < 4; i++) o2[i] = E * a[i] + o2[i];
  }

  denom += __shfl_xor(denom, 32, 64);
  #pragma unroll
  for (int i = 0; i < 4; i++){
    o2[i].x += __shfl_xor(o2[i].x, 32, 64);
    o2[i].y += __shfl_xor(o2[i].y, 32, 64);
  }
  float inv = 1.f / denom;
  float2v I = {inv, inv};
  #pragma unroll
  for (int i = 0; i < 4; i++) o2[i] = o2[i] * I;
  #pragma unroll
  for (int i = 0; i < 4; i++){
    o2[i].x += __shfl_xor(o2[i].x, 8, 64);  o2[i].y += __shfl_xor(o2[i].y, 8, 64);
    o2[i].x += __shfl_xor(o2[i].x, 16, 64); o2[i].y += __shfl_xor(o2[i].y, 16, 64);
  }
  int cb = (j & 7) * 8;
  float4 bg0 = *(const float4*)(bgat + cb);
  float4 bg1 = *(const float4*)(bgat + cb + 4);
  float4 wl0 = *(const float4*)(wlin + cb);
  float4 wl1 = *(const float4*)(wlin + cb + 4);
  float ov[8]  = {o2[0].x, o2[0].y, o2[1].x, o2[1].y, o2[2].x, o2[2].y, o2[3].x, o2[3].y};
  float bgv[8] = {bg0.x, bg0.y, bg0.z, bg0.w, bg1.x, bg1.y, bg1.z, bg1.w};
  float wlv[8] = {wl0.x, wl0.y, wl0.z, wl0.w, wl1.x, wl1.y, wl1.z, wl1.w};
  float r = 0.f;
  #pragma unroll
  for (int i = 0; i < 8; i++){
    float g = fmaxf(fmaf(ov[i], 0.25f, bgv[i]), 0.f);
    r = fmaf(g, wlv[i], r);
  }
  r = red8(r);
  if (lane == 0) out[node] = r + blin[0];
}

extern "C" void kernel_launch(void* const* d_in, const int* in_sizes, int n_in,
                              void* d_out, int out_size, void* d_ws, size_t ws_size,
                              hipStream_t stream){
  const float* x    = (const float*)d_in[0];
  const int* edge_index = (const int*)d_in[1];
  const float* Wg   = (const float*)d_in[3];
  const float* bgcn = (const float*)d_in[4];
  const float* Wl   = (const float*)d_in[5];
  const float* bl   = (const float*)d_in[6];
  const float* Wr   = (const float*)d_in[7];
  const float* br   = (const float*)d_in[8];
  const float* attw = (const float*)d_in[9];
  const float* bgat = (const float*)d_in[10];
  const float* wlin = (const float*)d_in[11];
  const float* blin = (const float*)d_in[12];
  float* out = (float*)d_out;

  const int N = in_sizes[0] / 128;
  const int E = in_sizes[1] / 2;
  const int* srcv = edge_index;
  const int* dstv = edge_index + E;

  char* w = (char*)d_ws;
  size_t o = 0;
  int* cnt = (int*)(w + o);            o += (((size_t)N * 4) + 255) & ~(size_t)255;
  int* cursor = (int*)(w + o);         o += (((size_t)N * 4) + 255) & ~(size_t)255;
  int* excl = (int*)(w + o);           o += (((size_t)N * 4) + 255) & ~(size_t)255;
  int* off = (int*)(w + o);            o += (((size_t)(N + 1) * 4) + 255) & ~(size_t)255;
  int* bsum = (int*)(w + o);           o += (2048 * 4 + 255) & ~(size_t)255;
  float* dinv = (float*)(w + o);       o += (((size_t)N * 4) + 255) & ~(size_t)255;
  float* S = (float*)(w + o);          o += (((size_t)N * 8 * 4) + 255) & ~(size_t)255;
  unsigned short* xw = (unsigned short*)(w + o);   o += (((size_t)N * 64 * 2) + 255) & ~(size_t)255;
  unsigned short* h = (unsigned short*)(w + o);    o += (((size_t)N * 64 * 2) + 255) & ~(size_t)255;
  unsigned short* xlr = (unsigned short*)(w + o);  o += (((size_t)N * 512 * 2) + 255) & ~(size_t)255;
  int* csr = (int*)(w + o);            o += (((size_t)E * 4) + 255) & ~(size_t)255;
  unsigned short* wp = (unsigned short*)(w + o);   o += (size_t)131072;  // 64x512 x {hi,lo}
  unsigned short* wp1 = (unsigned short*)(w + o);  o += (size_t)32768;   // 128x64 x {hi,lo}
  (void)o; (void)ws_size; (void)n_in; (void)out_size;

  const int nbN = (N + 255) / 256;
  const int nbE = (E + 255) / 256;
  const int nb4 = (N + 3) / 4;
  const int nb64 = (N + 63) / 64;

  CarbonGNN_36447092474498_initpack<<<nbN + 320, 256, 0, stream>>>(
      cnt, cursor, N, nbN, Wg, Wl, Wr, wp1, wp);
  CarbonGNN_36447092474498_histgemm1<<<nbE + nb64, 256, 0, stream>>>(
      dstv, E, cnt, nbE, x, wp1, xw, N);
  CarbonGNN_36447092474498_scan1<<<nbN, 256, 0, stream>>>(cnt, N, excl, bsum);
  CarbonGNN_36447092474498_scan3<<<nbN, 256, 0, stream>>>(excl, bsum, nbN, cnt, N, E, off, dinv);
  CarbonGNN_36447092474498_fill <<<nbE, 256, 0, stream>>>(srcv, dstv, E, off, cursor, csr);
  CarbonGNN_36447092474498_gcn  <<<nb4, 256, 0, stream>>>(xw, off, csr, dinv, bgcn, h, N);
  dim3 g2((N + 127) / 128, 2);
  CarbonGNN_36447092474498_gemm2<<<g2, 256, 0, stream>>>(h, wp, bl, br, attw, xlr, S, N);
  CarbonGNN_36447092474498_kernel<<<nb4, 256, 0, stream>>>(xlr, off, csr, attw, S, bgat, wlin, blin, out, N);
}

// Round 9
// 243.698 us; speedup vs baseline: 1.3260x; 1.2832x over previous
//
#include <hip/hip_runtime.h>

static __device__ inline float b2f(unsigned short u){
  union { unsigned int i; float f; } v; v.i = ((unsigned int)u) << 16; return v.f;
}
static __device__ inline unsigned short f2b(float f){
  union { float ff; unsigned int u; } v; v.ff = f;
  unsigned int xx = v.u;
  return (unsigned short)((xx + 0x7fffu + ((xx >> 16) & 1u)) >> 16);
}

typedef __attribute__((ext_vector_type(8))) short short8x;   // 8 bf16 (4 VGPRs)
typedef __attribute__((ext_vector_type(4))) float f32x4;
typedef __attribute__((ext_vector_type(2))) float float2v;   // -> v_pk_*_f32

// unpack one dword holding 2 bf16 -> float2 {lo, hi}
static __device__ inline float2v up2(unsigned int u){
  union { unsigned int i; float f; } a, b;
  a.i = u << 16; b.i = u & 0xffff0000u;
  float2v r; r.x = a.f; r.y = b.f; return r;
}

// 8-lane sum via DPP (VALU-only). Requires whole wave active (wave-uniform guards).
#define DPPADD(x, ctrl) \
  ((x) + __int_as_float(__builtin_amdgcn_update_dpp(0, __float_as_int(x), (ctrl), 0xf, 0xf, true)))
static __device__ inline float red8(float x){
  x = DPPADD(x, 0xb1);    // quad_perm [1,0,3,2]
  x = DPPADD(x, 0x4e);    // quad_perm [2,3,0,1]
  x = DPPADD(x, 0x141);   // row_half_mirror
  return x;
}

// ---------------- shared phase bodies ----------------

// Wg^T pack item (idx in [0,16384))
static __device__ inline void dev_wpack1_item(int idx, const float* __restrict__ Wg,
                                              unsigned short* __restrict__ wp1){
  int i    = idx & 7;
  int lane = (idx >> 3) & 63;
  int p    = (idx >> 9) & 1;
  int kt   = (idx >> 10) & 3;
  int ct   = idx >> 12;                            // 0..3
  int c = ct * 16 + (lane & 15);
  int k = kt * 32 + (lane >> 4) * 8 + i;
  float w = Wg[k * 64 + c];
  unsigned short hi = f2b(w);
  unsigned short outv = p ? f2b(w - b2f(hi)) : hi;
  int fb = ct * 8 + kt * 2 + p;
  wp1[(size_t)fb * 512 + lane * 8 + i] = outv;
}

// [Wl|Wr]^T pack item (idx in [0,65536))
static __device__ inline void dev_wpack2_item(int idx, const float* __restrict__ Wl,
                                              const float* __restrict__ Wr,
                                              unsigned short* __restrict__ wp){
  int i    = idx & 7;
  int lane = (idx >> 3) & 63;
  int p    = (idx >> 9) & 1;
  int kt   = (idx >> 10) & 1;
  int ct   = idx >> 11;                            // 0..31
  int c = ct * 16 + (lane & 15);
  int k = kt * 32 + (lane >> 4) * 8 + i;
  float w = (c < 256) ? Wl[k * 256 + c] : Wr[k * 256 + (c - 256)];
  unsigned short hi = f2b(w);
  unsigned short outv = p ? f2b(w - b2f(hi)) : hi;
  int fb = ct * 4 + kt * 2 + p;
  wp[(size_t)fb * 512 + lane * 8 + i] = outv;
}

// gemm1: virtual block vb covers 64 rows. D' = Wg^T . x^T via 16x16x32 MFMA.
static __device__ inline void dev_gemm1(int vb, int t, const float* __restrict__ x,
                                        const unsigned short* __restrict__ wp1,
                                        unsigned short* __restrict__ xw, int N){
  int lane = t & 63;
  int l15 = lane & 15;
  int lg = lane >> 4;
  int row = vb * 64 + (t >> 6) * 16 + l15;
  int rc = row < N ? row : N - 1;
  const float* xp = x + (size_t)rc * 128 + lg * 8;

  short8x xh[4], xlo[4];
  #pragma unroll
  for (int kt = 0; kt < 4; kt++){
    float4 a = *(const float4*)(xp + kt * 32);
    float4 b = *(const float4*)(xp + kt * 32 + 4);
    unsigned int h0, h1, h2, h3;
    asm("v_cvt_pk_bf16_f32 %0, %1, %2" : "=v"(h0) : "v"(a.x), "v"(a.y));
    asm("v_cvt_pk_bf16_f32 %0, %1, %2" : "=v"(h1) : "v"(a.z), "v"(a.w));
    asm("v_cvt_pk_bf16_f32 %0, %1, %2" : "=v"(h2) : "v"(b.x), "v"(b.y));
    asm("v_cvt_pk_bf16_f32 %0, %1, %2" : "=v"(h3) : "v"(b.z), "v"(b.w));
    union { unsigned int u[4]; short8x v; } H;
    H.u[0] = h0; H.u[1] = h1; H.u[2] = h2; H.u[3] = h3;
    xh[kt] = H.v;
    union { unsigned int u; float ff; } q;
    float r0, r1, r2, r3, r4, r5, r6, r7;
    q.u = h0 << 16;          r0 = a.x - q.ff;
    q.u = h0 & 0xffff0000u;  r1 = a.y - q.ff;
    q.u = h1 << 16;          r2 = a.z - q.ff;
    q.u = h1 & 0xffff0000u;  r3 = a.w - q.ff;
    q.u = h2 << 16;          r4 = b.x - q.ff;
    q.u = h2 & 0xffff0000u;  r5 = b.y - q.ff;
    q.u = h3 << 16;          r6 = b.z - q.ff;
    q.u = h3 & 0xffff0000u;  r7 = b.w - q.ff;
    unsigned int l0, l1, l2, l3;
    asm("v_cvt_pk_bf16_f32 %0, %1, %2" : "=v"(l0) : "v"(r0), "v"(r1));
    asm("v_cvt_pk_bf16_f32 %0, %1, %2" : "=v"(l1) : "v"(r2), "v"(r3));
    asm("v_cvt_pk_bf16_f32 %0, %1, %2" : "=v"(l2) : "v"(r4), "v"(r5));
    asm("v_cvt_pk_bf16_f32 %0, %1, %2" : "=v"(l3) : "v"(r6), "v"(r7));
    union { unsigned int u[4]; short8x v; } L;
    L.u[0] = l0; L.u[1] = l1; L.u[2] = l2; L.u[3] = l3;
    xlo[kt] = L.v;
  }

  #pragma unroll
  for (int ct = 0; ct < 4; ct++){
    f32x4 acc = {0.f, 0.f, 0.f, 0.f};
    #pragma unroll
    for (int kt = 0; kt < 4; kt++){
      const unsigned short* ap = wp1 + (size_t)(ct * 8 + kt * 2) * 512 + (size_t)lane * 8;
      short8x wh = *(const short8x*)(ap);
      short8x wl = *(const short8x*)(ap + 512);
      acc = __builtin_amdgcn_mfma_f32_16x16x32_bf16(wh, xh[kt], acc, 0, 0, 0);
      acc = __builtin_amdgcn_mfma_f32_16x16x32_bf16(wl, xh[kt], acc, 0, 0, 0);
      acc = __builtin_amdgcn_mfma_f32_16x16x32_bf16(wh, xlo[kt], acc, 0, 0, 0);
    }
    unsigned int p01, p23;
    asm("v_cvt_pk_bf16_f32 %0, %1, %2" : "=v"(p01) : "v"(acc[0]), "v"(acc[1]));
    asm("v_cvt_pk_bf16_f32 %0, %1, %2" : "=v"(p23) : "v"(acc[2]), "v"(acc[3]));
    if (row < N){
      uint2 pv; pv.x = p01; pv.y = p23;
      *(uint2*)(xw + (size_t)row * 64 + ct * 16 + lg * 4) = pv;
    }
  }
}

// ---------------- kernels (6 dispatches) ----------------

// init (zero bucket cursors) + weight packing, disjoint block ranges
__global__ __launch_bounds__(256) void CarbonGNN_36447092474498_initpack(
    int* __restrict__ gcur, int B, int nbG,
    const float* __restrict__ Wg, const float* __restrict__ Wl,
    const float* __restrict__ Wr,
    unsigned short* __restrict__ wp1, unsigned short* __restrict__ wp){
  int b = blockIdx.x;
  if (b < nbG){
    int i = b * 256 + threadIdx.x;
    if (i < B) gcur[i] = 0;
  } else if (b < nbG + 64){
    dev_wpack1_item((b - nbG) * 256 + threadIdx.x, Wg, wp1);
  } else {
    dev_wpack2_item((b - nbG - 64) * 256 + threadIdx.x, Wl, Wr, wp);
  }
}

// Phase A: bucket edges by dst>>7 (LDS hist + one global reservation per
// (block,bucket)); pack (dst&127)<<24 | src into per-bucket regions.
// Blocks nbA.. run gemm1 (independent).
__global__ __launch_bounds__(256) void CarbonGNN_36447092474498_bucketgemm1(
    const int* __restrict__ srcv, const int* __restrict__ dstv, int E,
    int nbA, int B, int CAP,
    int* __restrict__ gcur, unsigned int* __restrict__ bucketbuf,
    const float* __restrict__ x, const unsigned short* __restrict__ wp1,
    unsigned short* __restrict__ xw, int N){
  int blk = blockIdx.x;
  if (blk >= nbA){
    dev_gemm1(blk - nbA, threadIdx.x, x, wp1, xw, N);
    return;
  }
  __shared__ int lcnt[512];
  __shared__ int lbase[512];
  int t = threadIdx.x;
  int base = blk * 2048;
  for (int i = t; i < B; i += 256) lcnt[i] = 0;
  __syncthreads();
  int myb[8], myrank[8];
  unsigned int mypack[8];
  #pragma unroll
  for (int i = 0; i < 8; i++){
    int e = base + i * 256 + t;
    if (e < E){
      int d = dstv[e];
      int s = srcv[e];
      int bk = d >> 7;
      myb[i] = bk;
      myrank[i] = atomicAdd(&lcnt[bk], 1);
      mypack[i] = ((unsigned int)(d & 127) << 24) | (unsigned int)(s & 0xffffff);
    } else {
      myb[i] = -1; myrank[i] = 0; mypack[i] = 0;
    }
  }
  __syncthreads();
  for (int i = t; i < B; i += 256){
    int c = lcnt[i];
    lbase[i] = (c > 0) ? atomicAdd(&gcur[i], c) : 0;
  }
  __syncthreads();
  #pragma unroll
  for (int i = 0; i < 8; i++){
    if (myb[i] >= 0){
      int pos = lbase[myb[i]] + myrank[i];
      if (pos < CAP)
        bucketbuf[(size_t)myb[i] * CAP + pos] = mypack[i];
    }
  }
}

// Phase B: one 512-thread block per bucket. Redundant scan of bucket totals
// -> global edge base; LDS 128-bin hist + scan -> off/dinv; LDS-cursor
// scatter -> csr. No global atomics.
__global__ __launch_bounds__(512) void CarbonGNN_36447092474498_localcsr(
    const int* __restrict__ gcur, const unsigned int* __restrict__ bucketbuf,
    int B, int CAP, int E, int N,
    int* __restrict__ off, float* __restrict__ dinv, int* __restrict__ csr){
  __shared__ int gs[512];
  __shared__ int lcnt[128];
  __shared__ int ls[128];
  __shared__ int lcur[128];
  int t = threadIdx.x;
  int b = blockIdx.x;

  // scan clamped bucket totals (B <= 512)
  int v = 0;
  if (t < B){
    int c = gcur[t];
    v = c < CAP ? c : CAP;
  }
  gs[t] = v;
  __syncthreads();
  for (int ofs = 1; ofs < 512; ofs <<= 1){
    int y = (t >= ofs) ? gs[t - ofs] : 0;
    __syncthreads();
    gs[t] += y;
    __syncthreads();
  }
  int base_excl = (b == 0) ? 0 : gs[b - 1];
  int m = gs[b] - base_excl;            // this bucket's (clamped) edge count
  if (b == 0 && t == 0) off[N] = gs[B - 1];

  // local 128-bin histogram
  if (t < 128) lcnt[t] = 0;
  __syncthreads();
  const unsigned int* bb = bucketbuf + (size_t)b * CAP;
  for (int i = t; i < m; i += 512){
    unsigned int p = bb[i];
    atomicAdd(&lcnt[(p >> 24) & 127], 1);
  }
  __syncthreads();
  if (t < 128) ls[t] = lcnt[t];
  __syncthreads();
  for (int ofs = 1; ofs < 128; ofs <<= 1){
    int y = (t >= ofs && t < 128) ? ls[t - ofs] : 0;
    __syncthreads();
    if (t < 128) ls[t] += y;
    __syncthreads();
  }
  if (t < 128){
    int node = b * 128 + t;
    if (node < N){
      int excl = ls[t] - lcnt[t];
      off[node] = base_excl + excl;
      dinv[node] = rsqrtf((float)(lcnt[t] + 1));
      lcur[t] = excl;
    }
  }
  __syncthreads();
  // scatter src into csr
  for (int i = t; i < m; i += 512){
    unsigned int p = bb[i];
    int ln = (p >> 24) & 127;
    int r = atomicAdd(&lcur[ln], 1);
    csr[base_excl + r] = (int)(p & 0xffffff);
  }
}

// GCN aggregate: eighth-wave per edge — 8 lanes x 8 channels (one uint4/lane),
// 8 edges in flight per wave; combine groups with 3 shfl levels. (R6 proven.)
__global__ __launch_bounds__(256) void CarbonGNN_36447092474498_gcn(
    const unsigned short* __restrict__ xw, const int* __restrict__ off,
    const int* __restrict__ csr, const float* __restrict__ dinv,
    const float* __restrict__ bgcn, unsigned short* __restrict__ h, int N){
  int node = blockIdx.x * 4 + (threadIdx.x >> 6);
  if (node >= N) return;
  int lane = threadIdx.x & 63;
  int g = lane >> 3;           // edge slot 0..7
  int l8 = lane & 7;           // channel group
  int c8 = l8 * 8;
  float di = dinv[node];
  float2v o2[4] = {{0.f,0.f},{0.f,0.f},{0.f,0.f},{0.f,0.f}};
  int k0 = off[node], k1 = off[node + 1];
  int k = k0;
  for (; k + 7 < k1; k += 8){            // 8 edges per iter, 1 per group
    int s = csr[k + g];
    uint4 v = *(const uint4*)(xw + (size_t)s * 64 + c8);
    float d = dinv[s];
    float2v D = {d, d};
    o2[0] = D * up2(v.x) + o2[0];
    o2[1] = D * up2(v.y) + o2[1];
    o2[2] = D * up2(v.z) + o2[2];
    o2[3] = D * up2(v.w) + o2[3];
  }
  if (k < k1){                           // masked tail (<= 7 edges)
    int kk = k + g;
    bool act = kk < k1;
    int s = csr[act ? kk : k0];
    uint4 v = *(const uint4*)(xw + (size_t)s * 64 + c8);
    float d = act ? dinv[s] : 0.f;
    float2v D = {d, d};
    o2[0] = D * up2(v.x) + o2[0];
    o2[1] = D * up2(v.y) + o2[1];
    o2[2] = D * up2(v.z) + o2[2];
    o2[3] = D * up2(v.w) + o2[3];
  }
  // combine the 8 edge-groups (lanes with equal l8)
  #pragma unroll
  for (int i = 0; i < 4; i++){
    o2[i].x += __shfl_xor(o2[i].x, 8, 64);  o2[i].y += __shfl_xor(o2[i].y, 8, 64);
    o2[i].x += __shfl_xor(o2[i].x, 16, 64); o2[i].y += __shfl_xor(o2[i].y, 16, 64);
    o2[i].x += __shfl_xor(o2[i].x, 32, 64); o2[i].y += __shfl_xor(o2[i].y, 32, 64);
  }
  // self + bias + relu; group 0 writes
  uint4 su = *(const uint4*)(xw + (size_t)node * 64 + c8);
  float2v s01 = up2(su.x), s23 = up2(su.y), s45 = up2(su.z), s67 = up2(su.w);
  float4 bg0 = *(const float4*)(bgcn + c8);
  float4 bg1 = *(const float4*)(bgcn + c8 + 4);
  float v0 = fmaxf(fmaf(fmaf(s01.x, di, o2[0].x), di, bg0.x), 0.f);
  float v1 = fmaxf(fmaf(fmaf(s01.y, di, o2[0].y), di, bg0.y), 0.f);
  float v2 = fmaxf(fmaf(fmaf(s23.x, di, o2[1].x), di, bg0.z), 0.f);
  float v3 = fmaxf(fmaf(fmaf(s23.y, di, o2[1].y), di, bg0.w), 0.f);
  float v4 = fmaxf(fmaf(fmaf(s45.x, di, o2[2].x), di, bg1.x), 0.f);
  float v5 = fmaxf(fmaf(fmaf(s45.y, di, o2[2].y), di, bg1.y), 0.f);
  float v6 = fmaxf(fmaf(fmaf(s67.x, di, o2[3].x), di, bg1.z), 0.f);
  float v7 = fmaxf(fmaf(fmaf(s67.y, di, o2[3].y), di, bg1.w), 0.f);
  if (g == 0){
    unsigned int p01, p23, p45, p67;   // RNE pack, matches f2b
    asm("v_cvt_pk_bf16_f32 %0, %1, %2" : "=v"(p01) : "v"(v0), "v"(v1));
    asm("v_cvt_pk_bf16_f32 %0, %1, %2" : "=v"(p23) : "v"(v2), "v"(v3));
    asm("v_cvt_pk_bf16_f32 %0, %1, %2" : "=v"(p45) : "v"(v4), "v"(v5));
    asm("v_cvt_pk_bf16_f32 %0, %1, %2" : "=v"(p67) : "v"(v6), "v"(v7));
    uint4 hv; hv.x = p01; hv.y = p23; hv.z = p45; hv.w = p67;
    *(uint4*)(h + (size_t)node * 64 + c8) = hv;
  }
}

// gemm2 (MFMA): xlr[N,512] = h[N,64] @ [Wl|Wr][64,512] + b, bf16 out, plus
// S'[n][side*4+head] = 0.6*log2(e) * att_head . rounded(x_side[n, ...]).
__global__ __launch_bounds__(256) void CarbonGNN_36447092474498_gemm2(
    const unsigned short* __restrict__ h, const unsigned short* __restrict__ wp,
    const float* __restrict__ bl, const float* __restrict__ br,
    const float* __restrict__ attw,
    unsigned short* __restrict__ xlr, float* __restrict__ S, int N){
  int t = threadIdx.x;
  int lane = t & 63;
  int l15 = lane & 15;
  int lg = lane >> 4;
  int r0 = blockIdx.x * 128 + (t >> 6) * 32;
  int side = blockIdx.y;                 // 0: xl cols 0..255, 1: xr cols 256..511

  short8x bfr[2][2];
  #pragma unroll
  for (int rt = 0; rt < 2; rt++){
    int row = r0 + rt * 16 + l15;
    int rc = row < N ? row : (N - 1);
    const unsigned short* hp = h + (size_t)rc * 64 + lg * 8;
    bfr[rt][0] = *(const short8x*)(hp);
    bfr[rt][1] = *(const short8x*)(hp + 32);
  }

  const unsigned short* wpp = wp + (size_t)(side * 16) * 2048 + (size_t)lane * 8;
  short8x ah0 = *(const short8x*)(wpp);
  short8x al0 = *(const short8x*)(wpp + 512);
  short8x ah1 = *(const short8x*)(wpp + 1024);
  short8x al1 = *(const short8x*)(wpp + 1536);

  float sp0 = 0.f, sp1 = 0.f;
  for (int cl = 0; cl < 16; cl++){
    short8x ch0 = ah0, cg0 = al0, ch1 = ah1, cg1 = al1;
    if (cl < 15){
      const unsigned short* np = wpp + (size_t)(cl + 1) * 2048;
      ah0 = *(const short8x*)(np);
      al0 = *(const short8x*)(np + 512);
      ah1 = *(const short8x*)(np + 1024);
      al1 = *(const short8x*)(np + 1536);
    }
    int c4 = (side * 16 + cl) * 16 + lg * 4;
    float4 bias = (c4 < 256) ? *(const float4*)(bl + c4)
                             : *(const float4*)(br + (c4 - 256));
    float4 aw = *(const float4*)(attw + (c4 & 255));
    #pragma unroll
    for (int rt = 0; rt < 2; rt++){
      f32x4 acc = {0.f, 0.f, 0.f, 0.f};
      acc = __builtin_amdgcn_mfma_f32_16x16x32_bf16(ch0, bfr[rt][0], acc, 0, 0, 0);
      acc = __builtin_amdgcn_mfma_f32_16x16x32_bf16(cg0, bfr[rt][0], acc, 0, 0, 0);
      acc = __builtin_amdgcn_mfma_f32_16x16x32_bf16(ch1, bfr[rt][1], acc, 0, 0, 0);
      acc = __builtin_amdgcn_mfma_f32_16x16x32_bf16(cg1, bfr[rt][1], acc, 0, 0, 0);
      float v0 = acc[0] + bias.x;
      float v1 = acc[1] + bias.y;
      float v2 = acc[2] + bias.z;
      float v3 = acc[3] + bias.w;
      unsigned int p01, p23;                    // RNE pack, matches f2b
      asm("v_cvt_pk_bf16_f32 %0, %1, %2" : "=v"(p01) : "v"(v0), "v"(v1));
      asm("v_cvt_pk_bf16_f32 %0, %1, %2" : "=v"(p23) : "v"(v2), "v"(v3));
      int row = r0 + rt * 16 + l15;
      if (row < N){
        uint2 pv; pv.x = p01; pv.y = p23;
        *(uint2*)(xlr + (size_t)row * 512 + c4) = pv;
      }
      union { unsigned int u; float f; } q0, q1, q2, q3;
      q0.u = p01 << 16; q1.u = p01 & 0xffff0000u;
      q2.u = p23 << 16; q3.u = p23 & 0xffff0000u;
      float s = fmaf(aw.x, q0.f, fmaf(aw.y, q1.f, fmaf(aw.z, q2.f, aw.w * q3.f)));
      if (rt == 0) sp0 += s; else sp1 += s;
    }
    if ((cl & 3) == 3){
      int head = cl >> 2;
      float s0 = sp0, s1 = sp1;
      s0 += __shfl_xor(s0, 16, 64); s0 += __shfl_xor(s0, 32, 64);
      s1 += __shfl_xor(s1, 16, 64); s1 += __shfl_xor(s1, 32, 64);
      s0 *= 0.86561702453337803f;                // 0.6 * log2(e)
      s1 *= 0.86561702453337803f;
      if (lane < 16){
        int ra = r0 + l15;
        if (ra < N) S[(size_t)ra * 8 + side * 4 + head] = s0;
        int rb = r0 + 16 + l15;
        if (rb < N) S[(size_t)rb * 8 + side * 4 + head] = s1;
      }
      sp0 = 0.f; sp1 = 0.f;
    }
  }
}

// GATv2: exp2-domain anchored softmax; half-wave per edge, 4 edges/iter.
// (R6 proven form — no software pipeline.)
__global__ __launch_bounds__(256) void CarbonGNN_36447092474498_kernel(
    const unsigned short* __restrict__ xlr, const int* __restrict__ off,
    const int* __restrict__ csr, const float* __restrict__ attw,
    const float* __restrict__ S,
    const float* __restrict__ bgat, const float* __restrict__ wlin,
    const float* __restrict__ blin, float* __restrict__ out, int N){
  const float c04 = 0.57707801635558535f;      // 0.4 * log2(e)
  int node = blockIdx.x * 4 + (threadIdx.x >> 6);
  if (node >= N) return;
  int lane = threadIdx.x & 63;
  int half = lane >> 5;
  int j = lane & 31;
  int hd = j >> 3;
  int c8 = j * 8;
  const unsigned short* xrow = xlr + (size_t)node * 512;

  uint4 xru = *(const uint4*)(xrow + 256 + c8);
  float2v xr2[4] = {up2(xru.x), up2(xru.y), up2(xru.z), up2(xru.w)};
  float aw[8];
  {
    float4 a0 = *(const float4*)(attw + c8);
    float4 a1 = *(const float4*)(attw + c8 + 4);
    aw[0] = a0.x; aw[1] = a0.y; aw[2] = a0.z; aw[3] = a0.w;
    aw[4] = a1.x; aw[5] = a1.y; aw[6] = a1.z; aw[7] = a1.w;
  }

  uint4 xsu = *(const uint4*)(xrow + c8);
  float2v xs2[4] = {up2(xsu.x), up2(xsu.y), up2(xsu.z), up2(xsu.w)};
  float Rs = 0.f;
  #pragma unroll
  for (int i = 0; i < 4; i++){
    float2v z = xs2[i] + xr2[i];
    Rs = fmaf(aw[2 * i],     fabsf(z.x), Rs);
    Rs = fmaf(aw[2 * i + 1], fabsf(z.y), Rs);
  }
  Rs = red8(Rs);
  float base = -fmaf(c04, Rs, S[(size_t)node * 8 + hd]);

  float denom;
  float2v o2[4];
  if (half == 0){
    denom = 1.f;
    #pragma unroll
    for (int i = 0; i < 4; i++) o2[i] = xs2[i];
  } else {
    denom = 0.f;
    #pragma unroll
    for (int i = 0; i < 4; i++) o2[i] = (float2v){0.f, 0.f};
  }

  int k0 = off[node], k1 = off[node + 1];
  int k = k0;
  for (; k + 3 < k1; k += 4){            // 4 edges per iter, 2 per half
    int i0 = csr[k + half];
    int i1 = csr[k + 2 + half];
    uint4 v0 = *(const uint4*)(xlr + (size_t)i0 * 512 + c8);
    uint4 v1 = *(const uint4*)(xlr + (size_t)i1 * 512 + c8);
    float Sl0 = S[(size_t)i0 * 8 + hd];
    float Sl1 = S[(size_t)i1 * 8 + hd];
    float2v a0[4] = {up2(v0.x), up2(v0.y), up2(v0.z), up2(v0.w)};
    float2v a1[4] = {up2(v1.x), up2(v1.y), up2(v1.z), up2(v1.w)};
    float R0 = 0.f, R1 = 0.f;
    #pragma unroll
    for (int i = 0; i < 4; i++){
      float2v z0 = a0[i] + xr2[i];
      float2v z1 = a1[i] + xr2[i];
      float w0 = aw[2 * i], w1 = aw[2 * i + 1];
      R0 = fmaf(w0, fabsf(z0.x), R0); R0 = fmaf(w1, fabsf(z0.y), R0);
      R1 = fmaf(w0, fabsf(z1.x), R1); R1 = fmaf(w1, fabsf(z1.y), R1);
    }
    R0 = red8(R0);
    R1 = red8(R1);
    float e0 = exp2f(fmaf(c04, R0, Sl0 + base));
    float e1 = exp2f(fmaf(c04, R1, Sl1 + base));
    denom += e0 + e1;
    float2v E0 = {e0, e0}, E1 = {e1, e1};
    #pragma unroll
    for (int i = 0; i < 4; i++){
      o2[i] = E0 * a0[i] + o2[i];
      o2[i] = E1 * a1[i] + o2[i];
    }
  }
  for (; k < k1; k += 2){                // masked tail, 2 edges per iter
    int kk = k + half;
    bool act = kk < k1;
    int s = csr[act ? kk : k];
    uint4 v = *(const uint4*)(xlr + (size_t)s * 512 + c8);
    float Sl = S[(size_t)s * 8 + hd];
    float2v a[4] = {up2(v.x), up2(v.y), up2(v.z), up2(v.w)};
    float Rr = 0.f;
    #pragma unroll
    for (int i = 0; i < 4; i++){
      float2v z = a[i] + xr2[i];
      Rr = fmaf(aw[2 * i],     fabsf(z.x), Rr);
      Rr = fmaf(aw[2 * i + 1], fabsf(z.y), Rr);
    }
    Rr = red8(Rr);
    float e = act ? exp2f(fmaf(c04, Rr, Sl + base)) : 0.f;
    denom += e;
    float2v E = {e, e};
    #pragma unroll
    for (int i = 0; i < 4; i++) o2[i] = E * a[i] + o2[i];
  }

  denom += __shfl_xor(denom, 32, 64);
  #pragma unroll
  for (int i = 0; i < 4; i++){
    o2[i].x += __shfl_xor(o2[i].x, 32, 64);
    o2[i].y += __shfl_xor(o2[i].y, 32, 64);
  }
  float inv = 1.f / denom;
  float2v I = {inv, inv};
  #pragma unroll
  for (int i = 0; i < 4; i++) o2[i] = o2[i] * I;
  #pragma unroll
  for (int i = 0; i < 4; i++){
    o2[i].x += __shfl_xor(o2[i].x, 8, 64);  o2[i].y += __shfl_xor(o2[i].y, 8, 64);
    o2[i].x += __shfl_xor(o2[i].x, 16, 64); o2[i].y += __shfl_xor(o2[i].y, 16, 64);
  }
  int cb = (j & 7) * 8;
  float4 bg0 = *(const float4*)(bgat + cb);
  float4 bg1 = *(const float4*)(bgat + cb + 4);
  float4 wl0 = *(const float4*)(wlin + cb);
  float4 wl1 = *(const float4*)(wlin + cb + 4);
  float ov[8]  = {o2[0].x, o2[0].y, o2[1].x, o2[1].y, o2[2].x, o2[2].y, o2[3].x, o2[3].y};
  float bgv[8] = {bg0.x, bg0.y, bg0.z, bg0.w, bg1.x, bg1.y, bg1.z, bg1.w};
  float wlv[8] = {wl0.x, wl0.y, wl0.z, wl0.w, wl1.x, wl1.y, wl1.z, wl1.w};
  float r = 0.f;
  #pragma unroll
  for (int i = 0; i < 8; i++){
    float g = fmaxf(fmaf(ov[i], 0.25f, bgv[i]), 0.f);
    r = fmaf(g, wlv[i], r);
  }
  r = red8(r);
  if (lane == 0) out[node] = r + blin[0];
}

extern "C" void kernel_launch(void* const* d_in, const int* in_sizes, int n_in,
                              void* d_out, int out_size, void* d_ws, size_t ws_size,
                              hipStream_t stream){
  const float* x    = (const float*)d_in[0];
  const int* edge_index = (const int*)d_in[1];
  const float* Wg   = (const float*)d_in[3];
  const float* bgcn = (const float*)d_in[4];
  const float* Wl   = (const float*)d_in[5];
  const float* bl   = (const float*)d_in[6];
  const float* Wr   = (const float*)d_in[7];
  const float* br   = (const float*)d_in[8];
  const float* attw = (const float*)d_in[9];
  const float* bgat = (const float*)d_in[10];
  const float* wlin = (const float*)d_in[11];
  const float* blin = (const float*)d_in[12];
  float* out = (float*)d_out;

  const int N = in_sizes[0] / 128;
  const int E = in_sizes[1] / 2;
  const int* srcv = edge_index;
  const int* dstv = edge_index + E;

  const int B = (N + 127) >> 7;                  // buckets of 128 nodes (B <= 512 for N <= 65536)
  const int avg = (E + B - 1) / B;
  const int CAP = (avg * 7) / 4 + 128;           // ~37 sigma headroom for Binomial(E, 1/B)

  char* w = (char*)d_ws;
  size_t o = 0;
  int* gcur = (int*)(w + o);           o += (((size_t)B * 4) + 255) & ~(size_t)255;
  int* off = (int*)(w + o);            o += (((size_t)(N + 1) * 4) + 255) & ~(size_t)255;
  float* dinv = (float*)(w + o);       o += (((size_t)N * 4) + 255) & ~(size_t)255;
  float* S = (float*)(w + o);          o += (((size_t)N * 8 * 4) + 255) & ~(size_t)255;
  unsigned short* xw = (unsigned short*)(w + o);   o += (((size_t)N * 64 * 2) + 255) & ~(size_t)255;
  unsigned short* h = (unsigned short*)(w + o);    o += (((size_t)N * 64 * 2) + 255) & ~(size_t)255;
  unsigned short* xlr = (unsigned short*)(w + o);  o += (((size_t)N * 512 * 2) + 255) & ~(size_t)255;
  int* csr = (int*)(w + o);            o += (((size_t)E * 4) + 255) & ~(size_t)255;
  unsigned int* bucketbuf = (unsigned int*)(w + o); o += (((size_t)B * CAP * 4) + 255) & ~(size_t)255;
  unsigned short* wp = (unsigned short*)(w + o);   o += (size_t)131072;  // 64x512 x {hi,lo}
  unsigned short* wp1 = (unsigned short*)(w + o);  o += (size_t)32768;   // 128x64 x {hi,lo}
  (void)o; (void)ws_size; (void)n_in; (void)out_size;

  const int nbG = (B + 255) / 256;
  const int nbA = (E + 2047) / 2048;
  const int nb4 = (N + 3) / 4;
  const int nb64 = (N + 63) / 64;

  CarbonGNN_36447092474498_initpack<<<nbG + 320, 256, 0, stream>>>(
      gcur, B, nbG, Wg, Wl, Wr, wp1, wp);
  CarbonGNN_36447092474498_bucketgemm1<<<nbA + nb64, 256, 0, stream>>>(
      srcv, dstv, E, nbA, B, CAP, gcur, bucketbuf, x, wp1, xw, N);
  CarbonGNN_36447092474498_localcsr<<<B, 512, 0, stream>>>(
      gcur, bucketbuf, B, CAP, E, N, off, dinv, csr);
  CarbonGNN_36447092474498_gcn  <<<nb4, 256, 0, stream>>>(xw, off, csr, dinv, bgcn, h, N);
  dim3 g2((N + 127) / 128, 2);
  CarbonGNN_36447092474498_gemm2<<<g2, 256, 0, stream>>>(h, wp, bl, br, attw, xlr, S, N);
  CarbonGNN_36447092474498_kernel<<<nb4, 256, 0, stream>>>(xlr, off, csr, attw, S, bgat, wlin, blin, out, N);
}